// Round 1
// baseline (1292.058 us; speedup 1.0000x reference)
//
#include <hip/hip_runtime.h>
#include <hip/hip_bf16.h>

using f32x4  = __attribute__((ext_vector_type(4))) float;
using bf16x8 = __attribute__((ext_vector_type(8))) short;
using short8 = __attribute__((ext_vector_type(8))) short;

#define DEVINL __device__ __forceinline__

DEVINL short f2bf(float f) {
  unsigned u = __builtin_bit_cast(unsigned, f);
  u += 0x7fffu + ((u >> 16) & 1u);          // RNE
  return (short)(u >> 16);
}

#define GLDS16(g, l) __builtin_amdgcn_global_load_lds( \
    (const __attribute__((address_space(1))) void*)(g), \
    (__attribute__((address_space(3))) void*)(l), 16, 0, 0)

// ---------------------------------------------------------------- transpose
// out[c*R + r] = in[r*C + c]  (fp32 -> bf16), used to build B^T weight layouts
__global__ __launch_bounds__(256)
void transpose_bf16(const float* __restrict__ in, short* __restrict__ out, int R, int C) {
  int idx = blockIdx.x * 256 + threadIdx.x;
  if (idx >= R * C) return;
  int c = idx / R, r = idx % R;
  out[idx] = f2bf(in[(size_t)r * C + c]);
}

// ---------------------------------------------------------------- LayerNorm
// one wave per token (64 lanes x 8 ch = 512). REMAP=1: shift+window-partition dest.
template<int REMAP>
__global__ __launch_bounds__(256)
void ln_kernel(const float* __restrict__ X, const float* __restrict__ gamma,
               const float* __restrict__ beta, short* __restrict__ OUT) {
  const int lane = threadIdx.x & 63;
  const int wid  = threadIdx.x >> 6;
  const int t    = blockIdx.x * 4 + wid;
  const float* xp = X + (size_t)t * 512 + lane * 8;
  float4 a = *(const float4*)xp;
  float4 b = *(const float4*)(xp + 4);
  float s = a.x + a.y + a.z + a.w + b.x + b.y + b.z + b.w;
  float q = a.x*a.x + a.y*a.y + a.z*a.z + a.w*a.w
          + b.x*b.x + b.y*b.y + b.z*b.z + b.w*b.w;
#pragma unroll
  for (int d = 1; d < 64; d <<= 1) { s += __shfl_xor(s, d); q += __shfl_xor(q, d); }
  float mean = s * (1.0f / 512.0f);
  float var  = q * (1.0f / 512.0f) - mean * mean;
  float rstd = rsqrtf(var + 1e-5f);
  float4 g0 = *(const float4*)(gamma + lane * 8);
  float4 g1 = *(const float4*)(gamma + lane * 8 + 4);
  float4 b0 = *(const float4*)(beta + lane * 8);
  float4 b1 = *(const float4*)(beta + lane * 8 + 4);
  short8 o;
  o[0] = f2bf((a.x - mean) * rstd * g0.x + b0.x);
  o[1] = f2bf((a.y - mean) * rstd * g0.y + b0.y);
  o[2] = f2bf((a.z - mean) * rstd * g0.z + b0.z);
  o[3] = f2bf((a.w - mean) * rstd * g0.w + b0.w);
  o[4] = f2bf((b.x - mean) * rstd * g1.x + b1.x);
  o[5] = f2bf((b.y - mean) * rstd * g1.y + b1.y);
  o[6] = f2bf((b.z - mean) * rstd * g1.z + b1.z);
  o[7] = f2bf((b.w - mean) * rstd * g1.w + b1.w);
  size_t orow;
  if (REMAP) {
    int bb = t >> 12, l = t & 4095, hh = l >> 6, ww = l & 63;
    int hs = (hh + 60) & 63, ws2 = (ww + 60) & 63;   // (coord - 4) mod 64
    orow = (size_t)(bb * 64 + (hs >> 3) * 8 + (ws2 >> 3)) * 64 + (hs & 7) * 8 + (ws2 & 7);
  } else {
    orow = (size_t)t;
  }
  *(short8*)(OUT + orow * 512 + lane * 8) = o;
}

// ---------------------------------------------------------------- fused window attention
// block = 1 window (64 tokens), 4 waves; each wave processes 4 heads sequentially.
// LDS per wave (12KB): q[64][32] | k[64][32] | vT[32][64]; P[64][64] overlaps q+k.
__global__ __launch_bounds__(256)
void attn_fused(const short* __restrict__ XW, const short* __restrict__ WQKVT,
                const float* __restrict__ qkvb, const float* __restrict__ rpb,
                short* __restrict__ AOUT) {
  __shared__ short lds[4][6144];
  const int tid = threadIdx.x, lane = tid & 63, wid = tid >> 6;
  const int lr = lane & 15, lg = lane >> 4;
  const int win = blockIdx.x;
  const int wimg = win & 63, wh = wimg >> 3, ww = wimg & 7;
  short* qb = lds[wid];
  short* kb = lds[wid] + 2048;
  short* vb = lds[wid] + 4096;
  short* Pb = lds[wid];            // overlaps q,k (dead by then)
  const size_t xbase = (size_t)win * 64 * 512;
  const float scale = 0.17677669529663687f;   // 1/sqrt(32)

  for (int it = 0; it < 4; ++it) {
    const int head = wid * 4 + it;
    // ---- phase 1: qkv = xw @ Wqkv^T segments for this head (M=64,N=96,K=512)
    f32x4 acc[4][6] = {};
#pragma unroll 2
    for (int kt = 0; kt < 512; kt += 32) {
      bf16x8 a[4], b[6];
#pragma unroll
      for (int tm = 0; tm < 4; ++tm)
        a[tm] = *(const bf16x8*)(XW + xbase + (size_t)(tm * 16 + lr) * 512 + kt + lg * 8);
#pragma unroll
      for (int nt = 0; nt < 6; ++nt) {
        int ncol = (nt >> 1) * 512 + head * 32 + (nt & 1) * 16 + lr;
        b[nt] = *(const bf16x8*)(WQKVT + (size_t)ncol * 512 + kt + lg * 8);
      }
#pragma unroll
      for (int tm = 0; tm < 4; ++tm)
#pragma unroll
        for (int nt = 0; nt < 6; ++nt)
          acc[tm][nt] = __builtin_amdgcn_mfma_f32_16x16x32_bf16(a[tm], b[nt], acc[tm][nt], 0, 0, 0);
    }
    // ---- stage q,k (natural [n][d]) and v transposed [d][n], + qkv bias
#pragma unroll
    for (int nt = 0; nt < 6; ++nt) {
      const int dcol = (nt & 1) * 16 + lr;
      const float bbv = qkvb[(nt >> 1) * 512 + head * 32 + dcol];
#pragma unroll
      for (int tm = 0; tm < 4; ++tm)
#pragma unroll
        for (int e = 0; e < 4; ++e) {
          int n = tm * 16 + lg * 4 + e;
          short hv = f2bf(acc[tm][nt][e] + bbv);
          if ((nt >> 1) == 0)      qb[n * 32 + dcol] = hv;
          else if ((nt >> 1) == 1) kb[n * 32 + dcol] = hv;
          else                     vb[dcol * 64 + n] = hv;
        }
    }
    __syncthreads();
    // ---- phase 2: S = q k^T  (16x16x32, K=32 in one step)
    f32x4 sa[4][4] = {};
    {
      bf16x8 aq[4], bk[4];
#pragma unroll
      for (int tm = 0; tm < 4; ++tm) aq[tm] = *(const bf16x8*)(qb + (tm * 16 + lr) * 32 + lg * 8);
#pragma unroll
      for (int tn = 0; tn < 4; ++tn) bk[tn] = *(const bf16x8*)(kb + (tn * 16 + lr) * 32 + lg * 8);
#pragma unroll
      for (int tm = 0; tm < 4; ++tm)
#pragma unroll
        for (int tn = 0; tn < 4; ++tn)
          sa[tm][tn] = __builtin_amdgcn_mfma_f32_16x16x32_bf16(aq[tm], bk[tn], sa[tm][tn], 0, 0, 0);
    }
    __syncthreads();
    // ---- softmax with rel-pos bias + shift mask; defer 1/sum to output
    float inv[4][4];
#pragma unroll
    for (int tm = 0; tm < 4; ++tm) {
#pragma unroll
      for (int e = 0; e < 4; ++e) {
        const int n = tm * 16 + lg * 4 + e;
        const int i1 = n >> 3, j1 = n & 7;
        const int hc1 = wh * 8 + i1, wc1 = ww * 8 + j1;
        const int rg1 = (hc1 < 56 ? 0 : (hc1 < 60 ? 1 : 2)) * 3 + (wc1 < 56 ? 0 : (wc1 < 60 ? 1 : 2));
        float v[4];
        float mx = -3.0e38f;
#pragma unroll
        for (int tn = 0; tn < 4; ++tn) {
          const int m = tn * 16 + lr;
          const int i2 = m >> 3, j2 = m & 7;
          const int hc2 = wh * 8 + i2, wc2 = ww * 8 + j2;
          const int rg2 = (hc2 < 56 ? 0 : (hc2 < 60 ? 1 : 2)) * 3 + (wc2 < 56 ? 0 : (wc2 < 60 ? 1 : 2));
          float bias = rpb[((i1 - i2 + 7) * 15 + (j1 - j2 + 7)) * 16 + head];
          float val = sa[tm][tn][e] * scale + bias + (rg1 != rg2 ? -100.0f : 0.0f);
          v[tn] = val;
          mx = fmaxf(mx, val);
        }
#pragma unroll
        for (int d = 1; d < 16; d <<= 1) mx = fmaxf(mx, __shfl_xor(mx, d));
        float sum = 0.f;
#pragma unroll
        for (int tn = 0; tn < 4; ++tn) { v[tn] = __expf(v[tn] - mx); sum += v[tn]; }
#pragma unroll
        for (int d = 1; d < 16; d <<= 1) sum += __shfl_xor(sum, d);
        inv[tm][e] = 1.0f / sum;
#pragma unroll
        for (int tn = 0; tn < 4; ++tn) Pb[n * 64 + tn * 16 + lr] = f2bf(v[tn]);
      }
    }
    __syncthreads();
    // ---- phase 4: O = P @ V   (A=P[64x64], B=vT rows are d)
    f32x4 oa[4][2] = {};
#pragma unroll
    for (int ks = 0; ks < 2; ++ks) {
      bf16x8 pa[4], bv2[2];
#pragma unroll
      for (int tm = 0; tm < 4; ++tm) pa[tm] = *(const bf16x8*)(Pb + (tm * 16 + lr) * 64 + ks * 32 + lg * 8);
#pragma unroll
      for (int t2 = 0; t2 < 2; ++t2) bv2[t2] = *(const bf16x8*)(vb + (t2 * 16 + lr) * 64 + ks * 32 + lg * 8);
#pragma unroll
      for (int tm = 0; tm < 4; ++tm)
#pragma unroll
        for (int t2 = 0; t2 < 2; ++t2)
          oa[tm][t2] = __builtin_amdgcn_mfma_f32_16x16x32_bf16(pa[tm], bv2[t2], oa[tm][t2], 0, 0, 0);
    }
#pragma unroll
    for (int tm = 0; tm < 4; ++tm)
#pragma unroll
      for (int t2 = 0; t2 < 2; ++t2)
#pragma unroll
        for (int e = 0; e < 4; ++e) {
          const int n = tm * 16 + lg * 4 + e;
          AOUT[xbase + (size_t)n * 512 + head * 32 + t2 * 16 + lr] = f2bf(oa[tm][t2][e] * inv[tm][e]);
        }
    __syncthreads();
  }
}

// ---------------------------------------------------------------- 128x128 GEMM (m97 structure)
// A [M][K] bf16 row-major, BT [N][K] bf16 row-major. BK=32, 4 waves 2x2, 4x4 16-tiles/wave.
// EPI 0: proj  -> X2 fp32 at window-reversed+unshifted row, + x residual + bias
// EPI 1: fc1   -> H1 bf16, gelu(acc+bias)
// EPI 2: fc2   -> out fp32, acc + bias + X2 residual
template<int EPI>
__global__ __launch_bounds__(256, 2)
void gemm128(const short* __restrict__ A, const short* __restrict__ BT,
             const int N, const int K,
             const float* __restrict__ bias,
             const float* __restrict__ resid,
             float* __restrict__ outf, short* __restrict__ outh) {
  __shared__ short As[128 * 32];
  __shared__ short Bs[128 * 32];
  const int tid = threadIdx.x, lane = tid & 63, wid = tid >> 6;
  const int lr = lane & 15, lg = lane >> 4;
  const int wm = wid >> 1, wn = wid & 1;
  const int m0 = blockIdx.y * 128, n0 = blockIdx.x * 128;
  const int srow = lane >> 2;            // 0..15
  const int scol = (lane & 3) * 8;       // 0,8,16,24
  f32x4 acc[4][4] = {};
  for (int kt = 0; kt < K; kt += 32) {
#pragma unroll
    for (int c = 0; c < 2; ++c) {
      const int chunk = wid * 2 + c;     // 0..7, 16 rows each
      GLDS16(A  + (size_t)(m0 + chunk * 16 + srow) * K + kt + scol, As + chunk * 512);
      GLDS16(BT + (size_t)(n0 + chunk * 16 + srow) * K + kt + scol, Bs + chunk * 512);
    }
    __syncthreads();
    bf16x8 af[4], bf_[4];
#pragma unroll
    for (int t = 0; t < 4; ++t) af[t]  = *(const bf16x8*)(As + (wm * 64 + t * 16 + lr) * 32 + lg * 8);
#pragma unroll
    for (int t = 0; t < 4; ++t) bf_[t] = *(const bf16x8*)(Bs + (wn * 64 + t * 16 + lr) * 32 + lg * 8);
#pragma unroll
    for (int i = 0; i < 4; ++i)
#pragma unroll
      for (int j = 0; j < 4; ++j)
        acc[i][j] = __builtin_amdgcn_mfma_f32_16x16x32_bf16(af[i], bf_[j], acc[i][j], 0, 0, 0);
    __syncthreads();
  }
#pragma unroll
  for (int j = 0; j < 4; ++j) {
    const int col = n0 + wn * 64 + j * 16 + lr;
    const float bc = bias[col];
#pragma unroll
    for (int i = 0; i < 4; ++i)
#pragma unroll
      for (int e = 0; e < 4; ++e) {
        const int row = m0 + wm * 64 + i * 16 + lg * 4 + e;
        float v = acc[i][j][e] + bc;
        if (EPI == 0) {
          const int w = row >> 6, n = row & 63;
          const int bb = w >> 6, wi = w & 63;
          const int hs = (wi >> 3) * 8 + (n >> 3), ws2 = (wi & 7) * 8 + (n & 7);
          const int hh = (hs + 4) & 63, wwp = (ws2 + 4) & 63;
          const size_t orow = (size_t)bb * 4096 + hh * 64 + wwp;
          outf[orow * 512 + col] = resid[orow * 512 + col] + v;
        } else if (EPI == 1) {
          float g = 0.5f * v * (1.0f + erff(v * 0.70710678118654752f));
          outh[(size_t)row * N + col] = f2bf(g);
        } else {
          outf[(size_t)row * N + col] = v + resid[(size_t)row * N + col];
        }
      }
  }
}

// ---------------------------------------------------------------- launch
extern "C" void kernel_launch(void* const* d_in, const int* in_sizes, int n_in,
                              void* d_out, int out_size, void* d_ws, size_t ws_size,
                              hipStream_t stream) {
  (void)in_sizes; (void)n_in; (void)out_size; (void)ws_size;
  const float* x      = (const float*)d_in[0];
  const float* g1     = (const float*)d_in[1];
  const float* b1     = (const float*)d_in[2];
  const float* qkv_w  = (const float*)d_in[3];
  const float* qkv_b  = (const float*)d_in[4];
  const float* proj_w = (const float*)d_in[5];
  const float* proj_b = (const float*)d_in[6];
  const float* rpb    = (const float*)d_in[7];
  const float* g2     = (const float*)d_in[8];
  const float* b2     = (const float*)d_in[9];
  const float* fc1_w  = (const float*)d_in[10];
  const float* fc1_b  = (const float*)d_in[11];
  const float* fc2_w  = (const float*)d_in[12];
  const float* fc2_b  = (const float*)d_in[13];
  float* out = (float*)d_out;
  char* ws = (char*)d_ws;

  short* WQKVT  = (short*)(ws);                 // [1536][512] bf16   1.5MB
  short* WPROJT = (short*)(ws + 1572864);       // [512][512]         0.5MB
  short* WFC1T  = (short*)(ws + 2097152);       // [2048][512]        2MB
  short* WFC2T  = (short*)(ws + 4194304);       // [512][2048]        2MB
  float* X2     = (float*)(ws + 6291456);       // [65536][512] fp32  134MB
  short* ATT    = (short*)(ws + 140509184);     // [65536][512] bf16  64MB (later X2N)
  short* XW     = (short*)(ws + 207618048);     // [65536][512] bf16  64MB (inside H1 region)
  short* H1     = XW;                           // [65536][2048] bf16 256MB (after XW dead)
  short* X2N    = ATT;

  transpose_bf16<<<3072, 256, 0, stream>>>(qkv_w,  WQKVT, 512, 1536);
  transpose_bf16<<<1024, 256, 0, stream>>>(proj_w, WPROJT, 512, 512);
  transpose_bf16<<<4096, 256, 0, stream>>>(fc1_w,  WFC1T, 512, 2048);
  transpose_bf16<<<4096, 256, 0, stream>>>(fc2_w,  WFC2T, 2048, 512);

  ln_kernel<1><<<16384, 256, 0, stream>>>(x, g1, b1, XW);
  attn_fused<<<1024, 256, 0, stream>>>(XW, WQKVT, qkv_b, rpb, ATT);
  gemm128<0><<<dim3(4, 512), 256, 0, stream>>>(ATT, WPROJT, 512, 512, proj_b, x, X2, nullptr);
  ln_kernel<0><<<16384, 256, 0, stream>>>(X2, g2, b2, X2N);
  gemm128<1><<<dim3(16, 512), 256, 0, stream>>>(X2N, WFC1T, 2048, 512, fc1_b, nullptr, nullptr, H1);
  gemm128<2><<<dim3(4, 512), 256, 0, stream>>>(H1, WFC2T, 512, 2048, fc2_b, X2, out, nullptr);
}

// Round 2
// 1068.037 us; speedup vs baseline: 1.2097x; 1.2097x over previous
//
#include <hip/hip_runtime.h>
#include <hip/hip_bf16.h>

using f32x4  = __attribute__((ext_vector_type(4))) float;
using bf16x8 = __attribute__((ext_vector_type(8))) short;
using short8 = __attribute__((ext_vector_type(8))) short;

#define DEVINL __device__ __forceinline__

DEVINL short f2bf(float f) {
  unsigned u = __builtin_bit_cast(unsigned, f);
  u += 0x7fffu + ((u >> 16) & 1u);          // RNE
  return (short)(u >> 16);
}

#define GLDS16(g, l) __builtin_amdgcn_global_load_lds( \
    (const __attribute__((address_space(1))) void*)(g), \
    (__attribute__((address_space(3))) void*)(l), 16, 0, 0)

// ---------------------------------------------------------------- transpose
// out[c*R + r] = in[r*C + c]  (fp32 -> bf16), builds B^T weight layouts
__global__ __launch_bounds__(256)
void transpose_bf16(const float* __restrict__ in, short* __restrict__ out, int R, int C) {
  int idx = blockIdx.x * 256 + threadIdx.x;
  if (idx >= R * C) return;
  int c = idx / R, r = idx % R;
  out[idx] = f2bf(in[(size_t)r * C + c]);
}

// ---------------------------------------------------------------- bias expand
// BIASF[head][n][m] = rpb[rpi(n,m)][head]   (16x64x64 f32 = 256KB, L2-hot)
__global__ __launch_bounds__(256)
void bias_expand(const float* __restrict__ rpb, float* __restrict__ BIASF) {
  int idx = blockIdx.x * 256 + threadIdx.x;   // 65536
  int head = idx >> 12, n = (idx >> 6) & 63, m = idx & 63;
  int i1 = n >> 3, j1 = n & 7, i2 = m >> 3, j2 = m & 7;
  BIASF[idx] = rpb[((i1 - i2 + 7) * 15 + (j1 - j2 + 7)) * 16 + head];
}

// ---------------------------------------------------------------- LayerNorm
// one wave per token (64 lanes x 8 ch = 512). REMAP=1: shift+window-partition dest.
template<int REMAP>
__global__ __launch_bounds__(256)
void ln_kernel(const float* __restrict__ X, const float* __restrict__ gamma,
               const float* __restrict__ beta, short* __restrict__ OUT) {
  const int lane = threadIdx.x & 63;
  const int wid  = threadIdx.x >> 6;
  const int t    = blockIdx.x * 4 + wid;
  const float* xp = X + (size_t)t * 512 + lane * 8;
  float4 a = *(const float4*)xp;
  float4 b = *(const float4*)(xp + 4);
  float s = a.x + a.y + a.z + a.w + b.x + b.y + b.z + b.w;
  float q = a.x*a.x + a.y*a.y + a.z*a.z + a.w*a.w
          + b.x*b.x + b.y*b.y + b.z*b.z + b.w*b.w;
#pragma unroll
  for (int d = 1; d < 64; d <<= 1) { s += __shfl_xor(s, d); q += __shfl_xor(q, d); }
  float mean = s * (1.0f / 512.0f);
  float var  = q * (1.0f / 512.0f) - mean * mean;
  float rstd = rsqrtf(var + 1e-5f);
  float4 g0 = *(const float4*)(gamma + lane * 8);
  float4 g1 = *(const float4*)(gamma + lane * 8 + 4);
  float4 b0 = *(const float4*)(beta + lane * 8);
  float4 b1 = *(const float4*)(beta + lane * 8 + 4);
  short8 o;
  o[0] = f2bf((a.x - mean) * rstd * g0.x + b0.x);
  o[1] = f2bf((a.y - mean) * rstd * g0.y + b0.y);
  o[2] = f2bf((a.z - mean) * rstd * g0.z + b0.z);
  o[3] = f2bf((a.w - mean) * rstd * g0.w + b0.w);
  o[4] = f2bf((b.x - mean) * rstd * g1.x + b1.x);
  o[5] = f2bf((b.y - mean) * rstd * g1.y + b1.y);
  o[6] = f2bf((b.z - mean) * rstd * g1.z + b1.z);
  o[7] = f2bf((b.w - mean) * rstd * g1.w + b1.w);
  size_t orow;
  if (REMAP) {
    int bb = t >> 12, l = t & 4095, hh = l >> 6, ww = l & 63;
    int hs = (hh + 60) & 63, ws2 = (ww + 60) & 63;   // (coord - 4) mod 64
    orow = (size_t)(bb * 64 + (hs >> 3) * 8 + (ws2 >> 3)) * 64 + (hs & 7) * 8 + (ws2 & 7);
  } else {
    orow = (size_t)t;
  }
  *(short8*)(OUT + orow * 512 + lane * 8) = o;
}

// ---------------------------------------------------------------- attention core
// one wave = one (window, head). LDS: per-wave P[64][64] bf16, XOR-swizzled.
__global__ __launch_bounds__(256)
void attn_core(const short* __restrict__ Q, const short* __restrict__ Kb,
               const short* __restrict__ VT, const float* __restrict__ BIASF,
               short* __restrict__ AOUT) {
  __shared__ short P[4][4096];
  const int tid = threadIdx.x, lane = tid & 63, wid = tid >> 6;
  const int lr = lane & 15, lg = lane >> 4;
  const int gw = blockIdx.x * 4 + wid;
  const int win = gw >> 4, head = gw & 15;
  const int wimg = win & 63, wh = wimg >> 3, ww = wimg & 7;
  const size_t qbase = (size_t)win * 64 * 512 + head * 32;
  short* Pb = P[wid];

  // ---- S = q k^T (scale pre-folded into Q)
  bf16x8 aq[4], bk[4];
#pragma unroll
  for (int tm = 0; tm < 4; ++tm) aq[tm] = *(const bf16x8*)(Q  + qbase + (size_t)(tm * 16 + lr) * 512 + lg * 8);
#pragma unroll
  for (int tn = 0; tn < 4; ++tn) bk[tn] = *(const bf16x8*)(Kb + qbase + (size_t)(tn * 16 + lr) * 512 + lg * 8);
  f32x4 sa[4][4] = {};
#pragma unroll
  for (int tm = 0; tm < 4; ++tm)
#pragma unroll
    for (int tn = 0; tn < 4; ++tn)
      sa[tm][tn] = __builtin_amdgcn_mfma_f32_16x16x32_bf16(aq[tm], bk[tn], sa[tm][tn], 0, 0, 0);

  // ---- softmax (rows n = tm*16+lg*4+e; cols m = tn*16+lr), 1/sum deferred
  const float* bias_h = BIASF + head * 4096;
  const int i2 = (lr >> 3), j2 = lr & 7;     // within-tile m decomposition (i2 partial)
  float inv[4][4];
#pragma unroll
  for (int tm = 0; tm < 4; ++tm) {
#pragma unroll
    for (int e = 0; e < 4; ++e) {
      const int n = tm * 16 + lg * 4 + e;
      const int i1 = n >> 3, j1 = n & 7;
      const int rh1 = (wh == 7) ? 1 + (i1 >> 2) : 0;
      const int rw1 = (ww == 7) ? 1 + (j1 >> 2) : 0;
      float v[4];
      float mx = -3.0e38f;
#pragma unroll
      for (int tn = 0; tn < 4; ++tn) {
        const int m = tn * 16 + lr;
        const int mi = (m >> 3), mj = m & 7;
        const int rh2 = (wh == 7) ? 1 + (mi >> 2) : 0;
        const int rw2 = (ww == 7) ? 1 + (mj >> 2) : 0;
        float val = sa[tm][tn][e] + bias_h[n * 64 + m]
                  + ((rh1 != rh2 || rw1 != rw2) ? -100.0f : 0.0f);
        v[tn] = val;
        mx = fmaxf(mx, val);
      }
#pragma unroll
      for (int d = 1; d < 16; d <<= 1) mx = fmaxf(mx, __shfl_xor(mx, d));
      float sum = 0.f;
#pragma unroll
      for (int tn = 0; tn < 4; ++tn) { v[tn] = __expf(v[tn] - mx); sum += v[tn]; }
#pragma unroll
      for (int d = 1; d < 16; d <<= 1) sum += __shfl_xor(sum, d);
      inv[tm][e] = 1.0f / sum;
      const int sw = (n & 7) << 3;
#pragma unroll
      for (int tn = 0; tn < 4; ++tn) Pb[n * 64 + ((tn * 16 + lr) ^ sw)] = f2bf(v[tn]);
    }
  }
  __syncthreads();

  // ---- O = P @ V  (B from VT[win][head][d][n], contiguous global loads)
  f32x4 oa[4][2] = {};
  const short* vt = VT + (size_t)win * 32768 + head * 2048;
#pragma unroll
  for (int ks = 0; ks < 2; ++ks) {
    bf16x8 pa[4], bv[2];
#pragma unroll
    for (int tm = 0; tm < 4; ++tm) {
      const int r = tm * 16 + lr;
      pa[tm] = *(const bf16x8*)(Pb + r * 64 + ((ks * 32 + lg * 8) ^ ((r & 7) << 3)));
    }
#pragma unroll
    for (int t2 = 0; t2 < 2; ++t2) bv[t2] = *(const bf16x8*)(vt + (t2 * 16 + lr) * 64 + ks * 32 + lg * 8);
#pragma unroll
    for (int tm = 0; tm < 4; ++tm)
#pragma unroll
      for (int t2 = 0; t2 < 2; ++t2)
        oa[tm][t2] = __builtin_amdgcn_mfma_f32_16x16x32_bf16(pa[tm], bv[t2], oa[tm][t2], 0, 0, 0);
  }
#pragma unroll
  for (int tm = 0; tm < 4; ++tm)
#pragma unroll
    for (int t2 = 0; t2 < 2; ++t2)
#pragma unroll
      for (int e = 0; e < 4; ++e) {
        const int n = tm * 16 + lg * 4 + e;
        AOUT[((size_t)win * 64 + n) * 512 + head * 32 + t2 * 16 + lr] = f2bf(oa[tm][t2][e] * inv[tm][e]);
      }
}

// ---------------------------------------------------------------- 128x128 GEMM (m97 structure)
// A [M][K] bf16 row-major, BT [N][K] bf16 row-major. BK=32, 4 waves 2x2, 4x4 16-tiles/wave.
// EPI 0: proj  -> X2 fp32 at window-reversed+unshifted row, + x residual + bias
// EPI 1: fc1   -> H1 bf16, gelu(acc+bias)
// EPI 2: fc2   -> out fp32, acc + bias + X2 residual
// EPI 3: qkv   -> outh: Q (scaled) | K | VT[win][head][d][n], all bf16
template<int EPI>
__global__ __launch_bounds__(256, 2)
void gemm128(const short* __restrict__ A, const short* __restrict__ BT,
             const int N, const int K,
             const float* __restrict__ bias,
             const float* __restrict__ resid,
             float* __restrict__ outf, short* __restrict__ outh) {
  __shared__ short As[128 * 32];
  __shared__ short Bs[128 * 32];
  const int tid = threadIdx.x, lane = tid & 63, wid = tid >> 6;
  const int lr = lane & 15, lg = lane >> 4;
  const int wm = wid >> 1, wn = wid & 1;
  const int m0 = blockIdx.y * 128, n0 = blockIdx.x * 128;
  const int srow = lane >> 2;            // 0..15
  const int scol = (lane & 3) * 8;       // 0,8,16,24
  f32x4 acc[4][4] = {};
  for (int kt = 0; kt < K; kt += 32) {
#pragma unroll
    for (int c = 0; c < 2; ++c) {
      const int chunk = wid * 2 + c;     // 0..7, 16 rows each
      GLDS16(A  + (size_t)(m0 + chunk * 16 + srow) * K + kt + scol, As + chunk * 512);
      GLDS16(BT + (size_t)(n0 + chunk * 16 + srow) * K + kt + scol, Bs + chunk * 512);
    }
    __syncthreads();
    bf16x8 af[4], bf_[4];
#pragma unroll
    for (int t = 0; t < 4; ++t) af[t]  = *(const bf16x8*)(As + (wm * 64 + t * 16 + lr) * 32 + lg * 8);
#pragma unroll
    for (int t = 0; t < 4; ++t) bf_[t] = *(const bf16x8*)(Bs + (wn * 64 + t * 16 + lr) * 32 + lg * 8);
#pragma unroll
    for (int i = 0; i < 4; ++i)
#pragma unroll
      for (int j = 0; j < 4; ++j)
        acc[i][j] = __builtin_amdgcn_mfma_f32_16x16x32_bf16(af[i], bf_[j], acc[i][j], 0, 0, 0);
    __syncthreads();
  }
#pragma unroll
  for (int j = 0; j < 4; ++j) {
    const int col = n0 + wn * 64 + j * 16 + lr;
    const float bc = bias[col];
#pragma unroll
    for (int i = 0; i < 4; ++i)
#pragma unroll
      for (int e = 0; e < 4; ++e) {
        const int row = m0 + wm * 64 + i * 16 + lg * 4 + e;
        float v = acc[i][j][e] + bc;
        if (EPI == 0) {
          const int w = row >> 6, n = row & 63;
          const int bb = w >> 6, wi = w & 63;
          const int hs = (wi >> 3) * 8 + (n >> 3), ws2 = (wi & 7) * 8 + (n & 7);
          const int hh = (hs + 4) & 63, wwp = (ws2 + 4) & 63;
          const size_t orow = (size_t)bb * 4096 + hh * 64 + wwp;
          outf[orow * 512 + col] = resid[orow * 512 + col] + v;
        } else if (EPI == 1) {
          float g = 0.5f * v * (1.0f + erff(v * 0.70710678118654752f));
          outh[(size_t)row * N + col] = f2bf(g);
        } else if (EPI == 2) {
          outf[(size_t)row * N + col] = v + resid[(size_t)row * N + col];
        } else {
          // QKV epilogue: seg uniform per block (n0 multiple of 128 within 512-col segs)
          const int seg = col >> 9;
          if (seg == 0) {
            outh[(size_t)row * 512 + col] = f2bf(v * 0.17677669529663687f);  // Q * 1/sqrt(32)
          } else if (seg == 1) {
            outh[33554432 + (size_t)row * 512 + (col - 512)] = f2bf(v);      // K
          } else {
            const int cc = col - 1024;                                        // V^T
            outh[67108864 + (size_t)((row >> 6) * 16 + (cc >> 5)) * 2048 + (cc & 31) * 64 + (row & 63)] = f2bf(v);
          }
        }
      }
  }
}

// ---------------------------------------------------------------- launch
extern "C" void kernel_launch(void* const* d_in, const int* in_sizes, int n_in,
                              void* d_out, int out_size, void* d_ws, size_t ws_size,
                              hipStream_t stream) {
  (void)in_sizes; (void)n_in; (void)out_size; (void)ws_size;
  const float* x      = (const float*)d_in[0];
  const float* g1     = (const float*)d_in[1];
  const float* b1     = (const float*)d_in[2];
  const float* qkv_w  = (const float*)d_in[3];
  const float* qkv_b  = (const float*)d_in[4];
  const float* proj_w = (const float*)d_in[5];
  const float* proj_b = (const float*)d_in[6];
  const float* rpb    = (const float*)d_in[7];
  const float* g2     = (const float*)d_in[8];
  const float* b2     = (const float*)d_in[9];
  const float* fc1_w  = (const float*)d_in[10];
  const float* fc1_b  = (const float*)d_in[11];
  const float* fc2_w  = (const float*)d_in[12];
  const float* fc2_b  = (const float*)d_in[13];
  float* out = (float*)d_out;
  char* ws = (char*)d_ws;

  short* WQKVT  = (short*)(ws);                 // [1536][512] bf16   1.5MB
  short* WPROJT = (short*)(ws + 1572864);       // [512][512]         0.5MB
  short* WFC1T  = (short*)(ws + 2097152);       // [2048][512]        2MB
  short* WFC2T  = (short*)(ws + 4194304);       // [512][2048]        2MB
  float* X2     = (float*)(ws + 6291456);       // [65536][512] fp32  134MB
  float* BIASF  = (float*)(ws + 6291456);       // 256KB, aliases X2 head (dead before proj writes X2)
  short* ATT    = (short*)(ws + 140509184);     // [65536][512] bf16  64MB (X2N reuses after proj)
  short* XW     = (short*)(ws + 207618048);     // [65536][512] bf16  64MB  (slot R0)
  short* QB     = (short*)(ws + 274726912);     // Q|K|VT 3x64MB      (slots R1..R3)
  short* H1     = XW;                           // [65536][2048] bf16 256MB over R0..R3 (all dead)
  short* X2N    = ATT;

  transpose_bf16<<<3072, 256, 0, stream>>>(qkv_w,  WQKVT, 512, 1536);
  transpose_bf16<<<1024, 256, 0, stream>>>(proj_w, WPROJT, 512, 512);
  transpose_bf16<<<4096, 256, 0, stream>>>(fc1_w,  WFC1T, 512, 2048);
  transpose_bf16<<<4096, 256, 0, stream>>>(fc2_w,  WFC2T, 2048, 512);
  bias_expand<<<256, 256, 0, stream>>>(rpb, BIASF);

  ln_kernel<1><<<16384, 256, 0, stream>>>(x, g1, b1, XW);
  gemm128<3><<<dim3(12, 512), 256, 0, stream>>>(XW, WQKVT, 1536, 512, qkv_b, nullptr, nullptr, QB);
  attn_core<<<4096, 256, 0, stream>>>(QB, QB + 33554432, QB + 67108864, BIASF, ATT);
  gemm128<0><<<dim3(4, 512), 256, 0, stream>>>(ATT, WPROJT, 512, 512, proj_b, x, X2, nullptr);
  ln_kernel<0><<<16384, 256, 0, stream>>>(X2, g2, b2, X2N);
  gemm128<1><<<dim3(16, 512), 256, 0, stream>>>(X2N, WFC1T, 2048, 512, fc1_b, nullptr, nullptr, H1);
  gemm128<2><<<dim3(4, 512), 256, 0, stream>>>(H1, WFC2T, 512, 2048, fc2_b, X2, out, nullptr);
}